// Round 1
// baseline (936.458 us; speedup 1.0000x reference)
//
#include <hip/hip_runtime.h>
#include <hip/hip_bf16.h>

#define B_  64
#define T_  1024
#define H_  256
#define OUT_LEN_ 3072

// ---------------------------------------------------------------------------
// Weight transpose: w[O][I][K] (O=256,I=256,K=3) -> wt[I*3+K][O]
// Makes conv LDS staging a straight coalesced copy.
// ---------------------------------------------------------------------------
__global__ __launch_bounds__(256) void wtrans_kernel(const float* __restrict__ w,
                                                     float* __restrict__ wt) {
    int e = blockIdx.x * 256 + threadIdx.x;            // 0 .. 196607, coalesced read
    if (e < H_ * H_ * 3) {
        int o = e / (H_ * 3);
        int ik = e % (H_ * 3);
        wt[(size_t)ik * H_ + o] = w[e];
    }
}

// ---------------------------------------------------------------------------
// Fused conv1d(K=3, SAME) + bias + ReLU.
// Tile: 64 time steps x 64 out-channels per block (256 thr), 4x4 per thread.
// K-loop chunked over 32 input channels; X halo + transposed W staged in LDS.
// Per il-iter per thread: 5x ds_read_b128 (all 16B-aligned, <=2-way banks),
// 48 FMAs.
// ---------------------------------------------------------------------------
__global__ __launch_bounds__(256) void conv_relu_kernel(
    const float* __restrict__ in,     // [B][T][H]
    const float* __restrict__ wt,     // [I*3+K][O] transposed weights
    const float* __restrict__ bias,   // [O]
    float* __restrict__ outp)         // [B][T][H]
{
    __shared__ float Xs[32 * 68];        // [i][t], t in [0,66) halo, stride 68 (16B-aligned rows)
    __shared__ float Ws[32 * 3 * 64];    // [i][k][oo] contiguous

    const int tid = threadIdx.x;
    const int tx = tid & 15;             // out-channel group
    const int ty = tid >> 4;             // time group
    const int tloc = ty * 4;
    const int oloc = tx * 4;
    const int t0 = blockIdx.x * 64;
    const int o0 = blockIdx.y * 64;
    const int b  = blockIdx.z;

    const float* inb = in + (size_t)b * T_ * H_;

    float acc[4][4];
    float4 bv = *(const float4*)&bias[o0 + oloc];
    #pragma unroll
    for (int j = 0; j < 4; ++j) {
        acc[j][0] = bv.x; acc[j][1] = bv.y; acc[j][2] = bv.z; acc[j][3] = bv.w;
    }

    for (int ic0 = 0; ic0 < H_; ic0 += 32) {
        __syncthreads();
        // stage X halo chunk: Xs[i][t] = in[b][t0-1+t][ic0+i], zero outside [0,T)
        for (int e = tid; e < 66 * 32; e += 256) {
            int t = e >> 5;
            int i = e & 31;
            int gt = t0 - 1 + t;
            float v = 0.f;
            if (gt >= 0 && gt < T_) v = inb[(size_t)gt * H_ + ic0 + i];
            Xs[i * 68 + t] = v;
        }
        // stage W chunk (coalesced: wt rows are contiguous in o)
        for (int e = tid; e < 32 * 3 * 64; e += 256) {
            int ik = e >> 6;
            int oo = e & 63;
            Ws[e] = wt[(size_t)(ic0 * 3 + ik) * H_ + o0 + oo];
        }
        __syncthreads();

        #pragma unroll 4
        for (int il = 0; il < 32; ++il) {
            float4 xa = *(const float4*)&Xs[il * 68 + tloc];
            float4 xb = *(const float4*)&Xs[il * 68 + tloc + 4];
            float xv[8] = {xa.x, xa.y, xa.z, xa.w, xb.x, xb.y, xb.z, xb.w};
            const float* wrow = &Ws[il * 192];
            float4 w0 = *(const float4*)&wrow[0 * 64 + oloc];
            float4 w1 = *(const float4*)&wrow[1 * 64 + oloc];
            float4 w2 = *(const float4*)&wrow[2 * 64 + oloc];
            float wv[3][4] = {{w0.x, w0.y, w0.z, w0.w},
                              {w1.x, w1.y, w1.z, w1.w},
                              {w2.x, w2.y, w2.z, w2.w}};
            #pragma unroll
            for (int k = 0; k < 3; ++k)
                #pragma unroll
                for (int j = 0; j < 4; ++j)
                    #pragma unroll
                    for (int l = 0; l < 4; ++l)
                        acc[j][l] += xv[j + k] * wv[k][l];
        }
    }

    #pragma unroll
    for (int j = 0; j < 4; ++j) {
        int gt = t0 + tloc + j;
        float4 sv;
        sv.x = fmaxf(acc[j][0], 0.f);
        sv.y = fmaxf(acc[j][1], 0.f);
        sv.z = fmaxf(acc[j][2], 0.f);
        sv.w = fmaxf(acc[j][3], 0.f);
        *(float4*)&outp[((size_t)b * T_ + gt) * H_ + o0 + oloc] = sv;
    }
}

// ---------------------------------------------------------------------------
// Projection: logdur[b,t] = dot(h2[b,t,:], pw) + pb.  One wave per row.
// ---------------------------------------------------------------------------
__global__ __launch_bounds__(256) void proj_kernel(
    const float* __restrict__ h2, const float* __restrict__ pw,
    const float* __restrict__ pb, float* __restrict__ ld)
{
    int row  = blockIdx.x * 4 + (threadIdx.x >> 6);   // 0 .. B*T-1
    int lane = threadIdx.x & 63;
    const float4* hv4 = (const float4*)(h2 + (size_t)row * H_);
    const float4* pw4 = (const float4*)pw;
    float4 h = hv4[lane];
    float4 w = pw4[lane];
    float dot = h.x * w.x + h.y * w.y + h.z * w.z + h.w * w.w;
    #pragma unroll
    for (int d = 32; d > 0; d >>= 1) dot += __shfl_xor(dot, d, 64);
    if (lane == 0) ld[row] = dot + pb[0];
}

// ---------------------------------------------------------------------------
// Length regulator: per-block recomputed cumsum (wave scan), searchsorted
// (side='right'), row gather of x with masking. 128 output rows per block.
// ---------------------------------------------------------------------------
__global__ __launch_bounds__(256) void regulator_kernel(
    const float* __restrict__ x, const int* __restrict__ dur,
    float* __restrict__ out)
{
    const int b  = blockIdx.y;
    const int r0 = blockIdx.x * 128;
    const int tid = threadIdx.x;
    const int lane = tid & 63;
    const int wv = tid >> 6;

    __shared__ int cum[T_];
    __shared__ int wtot[4];
    __shared__ int sidx[128];

    // --- cumsum of durations row (4 elems/thread + wave scan + wave offsets)
    const int* drow = dur + (size_t)b * T_;
    int base = tid * 4;
    int d0 = drow[base + 0], d1 = drow[base + 1], d2 = drow[base + 2], d3 = drow[base + 3];
    int i0 = d0, i1 = i0 + d1, i2 = i1 + d2, i3 = i2 + d3;
    int lt = i3;
    int v = lt;
    #pragma unroll
    for (int delta = 1; delta < 64; delta <<= 1) {
        int u = __shfl_up(v, delta, 64);
        if (lane >= delta) v += u;
    }
    if (lane == 63) wtot[wv] = v;
    __syncthreads();
    int woff = 0;
    #pragma unroll
    for (int i = 0; i < 4; ++i)
        if (i < wv) woff += wtot[i];
    int excl = woff + v - lt;
    cum[base + 0] = excl + i0;
    cum[base + 1] = excl + i1;
    cum[base + 2] = excl + i2;
    cum[base + 3] = excl + i3;
    __syncthreads();

    // --- searchsorted(cum, p, side='right') for this block's 128 rows
    int tot = cum[T_ - 1];
    if (tid < 128) {
        int p = r0 + tid;
        int lo = 0, hi = T_;
        while (lo < hi) {
            int mid = (lo + hi) >> 1;
            if (cum[mid] <= p) lo = mid + 1; else hi = mid;
        }
        int idx = lo > (T_ - 1) ? (T_ - 1) : lo;
        sidx[tid] = (p < tot) ? idx : -1;
    }
    __syncthreads();

    // --- gather rows (one wave per row, float4 lanes; 4 rows per iter)
    const float4* x4 = (const float4*)(x + (size_t)b * T_ * H_);
    float4* o4 = (float4*)(out + ((size_t)b * OUT_LEN_ + r0) * H_);
    for (int rr = 0; rr < 128; rr += 4) {
        int r = rr + wv;
        int idx = sidx[r];
        float4 val;
        if (idx >= 0) val = x4[(size_t)idx * (H_ / 4) + lane];
        else          val = make_float4(0.f, 0.f, 0.f, 0.f);
        o4[(size_t)r * (H_ / 4) + lane] = val;
    }
}

// ---------------------------------------------------------------------------
extern "C" void kernel_launch(void* const* d_in, const int* in_sizes, int n_in,
                              void* d_out, int out_size, void* d_ws, size_t ws_size,
                              hipStream_t stream) {
    const float* x   = (const float*)d_in[0];
    const int*   dur = (const int*)d_in[1];
    const float* w1  = (const float*)d_in[2];
    const float* b1  = (const float*)d_in[3];
    const float* w2  = (const float*)d_in[4];
    const float* b2  = (const float*)d_in[5];
    const float* pw  = (const float*)d_in[6];
    const float* pb  = (const float*)d_in[7];

    float* out    = (float*)d_out;                       // [B][OUT_LEN][H]
    float* logdur = out + (size_t)B_ * OUT_LEN_ * H_;    // [B][T]

    // Scratch inside the (large) output region; regulator overwrites it last.
    float* h1  = out;                                    // [B][T][H] = 16.78M floats
    float* h2  = out + (size_t)B_ * T_ * H_;             // [B][T][H]
    float* wt1 = out + (size_t)2 * B_ * T_ * H_;         // 196608 floats
    float* wt2 = wt1 + (size_t)H_ * H_ * 3;

    wtrans_kernel<<<768, 256, 0, stream>>>(w1, wt1);
    wtrans_kernel<<<768, 256, 0, stream>>>(w2, wt2);

    dim3 cgrid(T_ / 64, H_ / 64, B_);
    conv_relu_kernel<<<cgrid, 256, 0, stream>>>(x,  wt1, b1, h1);
    conv_relu_kernel<<<cgrid, 256, 0, stream>>>(h1, wt2, b2, h2);

    proj_kernel<<<(B_ * T_) / 4, 256, 0, stream>>>(h2, pw, pb, logdur);

    regulator_kernel<<<dim3(OUT_LEN_ / 128, B_), 256, 0, stream>>>(x, dur, out);
}

// Round 2
// 474.861 us; speedup vs baseline: 1.9721x; 1.9721x over previous
//
#include <hip/hip_runtime.h>
#include <hip/hip_bf16.h>

#define B_  64
#define T_  1024
#define H_  256
#define OUT_LEN_ 3072

typedef __attribute__((ext_vector_type(8))) short short8v;
typedef __attribute__((ext_vector_type(4))) float floatx4;

__device__ __forceinline__ unsigned short f2bf_rne(float f) {
    unsigned int u = __float_as_uint(f);
    u += 0x7FFFu + ((u >> 16) & 1u);
    return (unsigned short)(u >> 16);
}
__device__ __forceinline__ float bf2f(unsigned short h) {
    return __uint_as_float(((unsigned int)h) << 16);
}

// ---------------------------------------------------------------------------
// fp32 -> (hi, lo) bf16 split of x. 8 elems/thread, vectorized.
// ---------------------------------------------------------------------------
__global__ __launch_bounds__(256) void convert_x_kernel(
    const float* __restrict__ x, unsigned short* __restrict__ xh,
    unsigned short* __restrict__ xl)
{
    size_t i = (size_t)blockIdx.x * 256 + threadIdx.x;   // one per 8 floats
    const float4* x4 = (const float4*)x;
    float4 v0 = x4[i * 2], v1 = x4[i * 2 + 1];
    float v[8] = {v0.x, v0.y, v0.z, v0.w, v1.x, v1.y, v1.z, v1.w};
    short8v hvec, lvec;
    #pragma unroll
    for (int j = 0; j < 8; ++j) {
        unsigned short h = f2bf_rne(v[j]);
        hvec[j] = (short)h;
        lvec[j] = (short)f2bf_rne(v[j] - bf2f(h));
    }
    *(short8v*)(xh + i * 8) = hvec;
    *(short8v*)(xl + i * 8) = lvec;
}

// ---------------------------------------------------------------------------
// w[O][I][3] fp32 -> wq_hi/wq_lo [O][3][I] bf16 (tap-major for conv staging)
// ---------------------------------------------------------------------------
__global__ __launch_bounds__(256) void convert_w_kernel(
    const float* __restrict__ w, unsigned short* __restrict__ wh,
    unsigned short* __restrict__ wl)
{
    int e = blockIdx.x * 256 + threadIdx.x;              // coalesced read
    if (e < H_ * H_ * 3) {
        int o = e / (H_ * 3);
        int rem = e % (H_ * 3);
        int ic = rem / 3;
        int tap = rem % 3;
        float v = w[e];
        unsigned short h = f2bf_rne(v);
        unsigned short l = f2bf_rne(v - bf2f(h));
        int dst = o * (3 * H_) + tap * H_ + ic;
        wh[dst] = h;
        wl[dst] = l;
    }
}

// ---------------------------------------------------------------------------
// Conv1d(K=3, SAME) + bias + ReLU via split-precision bf16 MFMA.
// Block: 64 t x 64 oc, 4 waves (2x2), wave tile 32x32 (2x2 frags 16x16).
// K-chunks of 32 input channels. LDS: X halo rows XOR-swizzled
// (byte ^= (row&3)<<4, conflict-free b128); W at 192B row stride
// (naturally conflict-free). 3 MFMAs per frag pair: hh + hl + lh.
// ---------------------------------------------------------------------------
template <bool OUTF32>
__global__ __launch_bounds__(256) void conv_mfma_kernel(
    const unsigned short* __restrict__ ahi, const unsigned short* __restrict__ alo, // [B][T][H]
    const unsigned short* __restrict__ whi, const unsigned short* __restrict__ wlo, // [O][3][H]
    const float* __restrict__ bias,
    unsigned short* __restrict__ ohi, unsigned short* __restrict__ olo,
    float* __restrict__ of32)
{
    __shared__ __align__(16) char lds[33024];
    char* XsH = lds;                 // 66 rows * 64B = 4224
    char* XsL = lds + 4224;          // 4224
    char* WsH = lds + 8448;          // 64 rows * 192B = 12288
    char* WsL = lds + 20736;         // 12288

    const int tid = threadIdx.x;
    const int t0 = blockIdx.x * 64;
    const int o0 = blockIdx.y * 64;
    const int b  = blockIdx.z;
    const int lane = tid & 63;
    const int wave = tid >> 6;
    const int r = lane & 15;         // frag row/col
    const int g = lane >> 4;         // k-group (8 bf16 per group)
    const int wm = wave >> 1;        // wave row (time)
    const int wn = wave & 1;         // wave col (oc)

    const size_t abase = (size_t)b * T_ * H_;

    floatx4 acc[2][2];
    #pragma unroll
    for (int fn = 0; fn < 2; ++fn) {
        float bv = bias[o0 + wn * 32 + fn * 16 + r];
        #pragma unroll
        for (int fm = 0; fm < 2; ++fm)
            acc[fm][fn] = (floatx4){bv, bv, bv, bv};
    }

    for (int ic0 = 0; ic0 < H_; ic0 += 32) {
        __syncthreads();
        // --- stage X halo chunk (hi+lo): rows t=0..65 <-> global t0-1+t, 32 ic
        for (int p = tid; p < 528; p += 256) {
            int arr = (p >= 264);
            int pi = arr ? p - 264 : p;
            int row = pi >> 2;
            int grp = pi & 3;
            int gt = t0 - 1 + row;
            uint4 val = make_uint4(0u, 0u, 0u, 0u);
            if (gt >= 0 && gt < T_) {
                const unsigned short* src =
                    (arr ? alo : ahi) + abase + (size_t)gt * H_ + ic0 + grp * 8;
                val = *(const uint4*)src;
            }
            char* dst = (arr ? XsL : XsH) + row * 64 + ((grp * 16) ^ ((row & 3) << 4));
            *(uint4*)dst = val;
        }
        // --- stage W chunk (hi+lo): Ws[oc][tap*64B + grp*16B]
        #pragma unroll
        for (int it = 0; it < 6; ++it) {
            int p = tid + it * 256;
            int arr = (p >= 768);
            int pi = arr ? p - 768 : p;
            int oc = pi / 12;
            int j = pi % 12;
            int tap = j >> 2;
            int grp = j & 3;
            const unsigned short* src =
                (arr ? wlo : whi) + (size_t)(o0 + oc) * (3 * H_) + tap * H_ + ic0 + grp * 8;
            uint4 val = *(const uint4*)src;
            char* dst = (arr ? WsL : WsH) + oc * 192 + tap * 64 + grp * 16;
            *(uint4*)dst = val;
        }
        __syncthreads();

        #pragma unroll
        for (int tap = 0; tap < 3; ++tap) {
            short8v aH[2], aL[2], bH[2], bL[2];
            #pragma unroll
            for (int fm = 0; fm < 2; ++fm) {
                int row = wm * 32 + fm * 16 + r + tap;      // Xs row (halo offset built in)
                int off = row * 64 + ((g * 16) ^ ((row & 3) << 4));
                aH[fm] = *(const short8v*)(XsH + off);
                aL[fm] = *(const short8v*)(XsL + off);
            }
            #pragma unroll
            for (int fn = 0; fn < 2; ++fn) {
                int oc = wn * 32 + fn * 16 + r;
                int off = oc * 192 + tap * 64 + g * 16;
                bH[fn] = *(const short8v*)(WsH + off);
                bL[fn] = *(const short8v*)(WsL + off);
            }
            #pragma unroll
            for (int fm = 0; fm < 2; ++fm)
                #pragma unroll
                for (int fn = 0; fn < 2; ++fn) {
                    acc[fm][fn] = __builtin_amdgcn_mfma_f32_16x16x32_bf16(
                        aH[fm], bH[fn], acc[fm][fn], 0, 0, 0);
                    acc[fm][fn] = __builtin_amdgcn_mfma_f32_16x16x32_bf16(
                        aH[fm], bL[fn], acc[fm][fn], 0, 0, 0);
                    acc[fm][fn] = __builtin_amdgcn_mfma_f32_16x16x32_bf16(
                        aL[fm], bH[fn], acc[fm][fn], 0, 0, 0);
                }
        }
    }

    // --- epilogue: C/D layout col=lane&15, row=(lane>>4)*4+reg (m89-verified)
    #pragma unroll
    for (int fm = 0; fm < 2; ++fm)
        #pragma unroll
        for (int fn = 0; fn < 2; ++fn) {
            int trow = t0 + wm * 32 + fm * 16 + g * 4;
            int o = o0 + wn * 32 + fn * 16 + r;
            #pragma unroll
            for (int reg = 0; reg < 4; ++reg) {
                float v = fmaxf(acc[fm][fn][reg], 0.f);
                size_t oidx = ((size_t)b * T_ + trow + reg) * H_ + o;
                if constexpr (OUTF32) {
                    of32[oidx] = v;
                } else {
                    unsigned short h = f2bf_rne(v);
                    ohi[oidx] = h;
                    olo[oidx] = f2bf_rne(v - bf2f(h));
                }
            }
        }
}

// ---------------------------------------------------------------------------
// Projection: logdur[row] = dot(h2[row,:], pw) + pb. One wave per row.
// ---------------------------------------------------------------------------
__global__ __launch_bounds__(256) void proj_kernel(
    const float* __restrict__ h2, const float* __restrict__ pw,
    const float* __restrict__ pb, float* __restrict__ ld)
{
    int row  = blockIdx.x * 4 + (threadIdx.x >> 6);
    int lane = threadIdx.x & 63;
    const float4* hv4 = (const float4*)(h2 + (size_t)row * H_);
    const float4* pw4 = (const float4*)pw;
    float4 h = hv4[lane];
    float4 w = pw4[lane];
    float dot = h.x * w.x + h.y * w.y + h.z * w.z + h.w * w.w;
    #pragma unroll
    for (int d = 32; d > 0; d >>= 1) dot += __shfl_xor(dot, d, 64);
    if (lane == 0) ld[row] = dot + pb[0];
}

// ---------------------------------------------------------------------------
// Length regulator (unchanged from R1, verified correct).
// ---------------------------------------------------------------------------
__global__ __launch_bounds__(256) void regulator_kernel(
    const float* __restrict__ x, const int* __restrict__ dur,
    float* __restrict__ out)
{
    const int b  = blockIdx.y;
    const int r0 = blockIdx.x * 128;
    const int tid = threadIdx.x;
    const int lane = tid & 63;
    const int wv = tid >> 6;

    __shared__ int cum[T_];
    __shared__ int wtot[4];
    __shared__ int sidx[128];

    const int* drow = dur + (size_t)b * T_;
    int base = tid * 4;
    int d0 = drow[base + 0], d1 = drow[base + 1], d2 = drow[base + 2], d3 = drow[base + 3];
    int i0 = d0, i1 = i0 + d1, i2 = i1 + d2, i3 = i2 + d3;
    int lt = i3;
    int v = lt;
    #pragma unroll
    for (int delta = 1; delta < 64; delta <<= 1) {
        int u = __shfl_up(v, delta, 64);
        if (lane >= delta) v += u;
    }
    if (lane == 63) wtot[wv] = v;
    __syncthreads();
    int woff = 0;
    #pragma unroll
    for (int i = 0; i < 4; ++i)
        if (i < wv) woff += wtot[i];
    int excl = woff + v - lt;
    cum[base + 0] = excl + i0;
    cum[base + 1] = excl + i1;
    cum[base + 2] = excl + i2;
    cum[base + 3] = excl + i3;
    __syncthreads();

    int tot = cum[T_ - 1];
    if (tid < 128) {
        int p = r0 + tid;
        int lo = 0, hi = T_;
        while (lo < hi) {
            int mid = (lo + hi) >> 1;
            if (cum[mid] <= p) lo = mid + 1; else hi = mid;
        }
        int idx = lo > (T_ - 1) ? (T_ - 1) : lo;
        sidx[tid] = (p < tot) ? idx : -1;
    }
    __syncthreads();

    const float4* x4 = (const float4*)(x + (size_t)b * T_ * H_);
    float4* o4 = (float4*)(out + ((size_t)b * OUT_LEN_ + r0) * H_);
    for (int rr = 0; rr < 128; rr += 4) {
        int rw = rr + wv;
        int idx = sidx[rw];
        float4 val;
        if (idx >= 0) val = x4[(size_t)idx * (H_ / 4) + lane];
        else          val = make_float4(0.f, 0.f, 0.f, 0.f);
        o4[(size_t)rw * (H_ / 4) + lane] = val;
    }
}

// ---------------------------------------------------------------------------
extern "C" void kernel_launch(void* const* d_in, const int* in_sizes, int n_in,
                              void* d_out, int out_size, void* d_ws, size_t ws_size,
                              hipStream_t stream) {
    const float* x   = (const float*)d_in[0];
    const int*   dur = (const int*)d_in[1];
    const float* w1  = (const float*)d_in[2];
    const float* b1  = (const float*)d_in[3];
    const float* w2  = (const float*)d_in[4];
    const float* b2  = (const float*)d_in[5];
    const float* pw  = (const float*)d_in[6];
    const float* pb  = (const float*)d_in[7];

    float* out = (float*)d_out;                          // [B][OUT_LEN][H] + [B][T]
    char*  p   = (char*)d_out;

    // Scratch layout inside d_out (201.6 MB total). Peak live use 136 MB.
    // xhi/xlo dead after conv1 -> h2 (fp32) reuses offset 0.
    unsigned short* xhi  = (unsigned short*)(p);                       // 33.5 MB
    unsigned short* xlo  = (unsigned short*)(p + 33554432u);           // 33.5 MB
    unsigned short* h1hi = (unsigned short*)(p + 67108864u);           // 33.5 MB
    unsigned short* h1lo = (unsigned short*)(p + 100663296u);          // 33.5 MB
    unsigned short* w1qh = (unsigned short*)(p + 134217728u);          // 384 KB
    unsigned short* w1ql = (unsigned short*)(p + 134610944u);
    unsigned short* w2qh = (unsigned short*)(p + 135004160u);
    unsigned short* w2ql = (unsigned short*)(p + 135397376u);
    float* h2 = (float*)(p);                                           // 67 MB (after conv1)
    float* logdur = out + (size_t)B_ * OUT_LEN_ * H_;

    convert_x_kernel<<<8192, 256, 0, stream>>>(x, xhi, xlo);
    convert_w_kernel<<<768, 256, 0, stream>>>(w1, w1qh, w1ql);
    convert_w_kernel<<<768, 256, 0, stream>>>(w2, w2qh, w2ql);

    dim3 cgrid(T_ / 64, H_ / 64, B_);
    conv_mfma_kernel<false><<<cgrid, 256, 0, stream>>>(
        xhi, xlo, w1qh, w1ql, b1, h1hi, h1lo, nullptr);
    conv_mfma_kernel<true><<<cgrid, 256, 0, stream>>>(
        h1hi, h1lo, w2qh, w2ql, b2, nullptr, nullptr, h2);

    proj_kernel<<<(B_ * T_) / 4, 256, 0, stream>>>(h2, pw, pb, logdur);

    regulator_kernel<<<dim3(OUT_LEN_ / 128, B_), 256, 0, stream>>>(x, dur, out);
}

// Round 3
// 404.914 us; speedup vs baseline: 2.3127x; 1.1727x over previous
//
#include <hip/hip_runtime.h>
#include <hip/hip_bf16.h>

#define B_  64
#define T_  1024
#define H_  256
#define OUT_LEN_ 3072

typedef __attribute__((ext_vector_type(8))) short short8v;
typedef __attribute__((ext_vector_type(4))) float floatx4;

__device__ __forceinline__ unsigned short f2bf_rne(float f) {
    unsigned int u = __float_as_uint(f);
    u += 0x7FFFu + ((u >> 16) & 1u);
    return (unsigned short)(u >> 16);
}
__device__ __forceinline__ float bf2f(unsigned short h) {
    return __uint_as_float(((unsigned int)h) << 16);
}

// ---------------------------------------------------------------------------
// w[O][I][3] fp32 -> wq bf16 hi/lo limbs in staging-friendly layout:
// idx(c,arr,tap,grp,o,el) = ((((c*2+arr)*3+tap)*4+grp)*256 + o)*8 + el
// where ic = c*32 + grp*8 + el.  Conv W-staging then reads 16B chunks fully
// coalesced across oc.
// ---------------------------------------------------------------------------
__global__ __launch_bounds__(256) void convert_w_kernel(
    const float* __restrict__ w, unsigned short* __restrict__ wq)
{
    int e = blockIdx.x * 256 + threadIdx.x;          // coalesced read
    if (e >= H_ * H_ * 3) return;
    int o = e / (H_ * 3);
    int rem = e - o * (H_ * 3);
    int ic = rem / 3;
    int tap = rem - ic * 3;
    float v = w[e];
    unsigned short h = f2bf_rne(v);
    unsigned short l = f2bf_rne(v - bf2f(h));
    int c = ic >> 5, grp = (ic >> 3) & 3, el = ic & 7;
    size_t hi_idx = ((((size_t)(c * 2 + 0) * 3 + tap) * 4 + grp) * 256 + o) * 8 + el;
    size_t lo_idx = ((((size_t)(c * 2 + 1) * 3 + tap) * 4 + grp) * 256 + o) * 8 + el;
    wq[hi_idx] = h;
    wq[lo_idx] = l;
}

// ---------------------------------------------------------------------------
__global__ __launch_bounds__(256) void init_ld_kernel(float* __restrict__ ld,
                                                      const float* __restrict__ pb) {
    int i = blockIdx.x * 256 + threadIdx.x;
    if (i < B_ * T_) ld[i] = pb[0];
}

// ---------------------------------------------------------------------------
// Conv1d(K=3, SAME) + bias + ReLU, split-precision bf16 MFMA (hh+hl+lh).
// Block tile 128t x 128oc, 256 thr = 4 waves (2x2), wave tile 64x64
// (4x4 frags of 16x16x32).  ic chunks of 32.
// LDS strides padded for bank-period 8 (conflict-free b128): X rows 80B,
// W rows 208B.
// MODE 0: input fp32 x (convert inline), output packed u32 (bf16 hi|lo<<16).
// MODE 1: input packed u32, epilogue fuses projection: logdur += relu(v)*pw.
// ---------------------------------------------------------------------------
template <int MODE>
__global__ __launch_bounds__(256, 2) void conv_mfma_kernel(
    const float* __restrict__ xin,          // MODE 0
    const unsigned int* __restrict__ pin,   // MODE 1
    const unsigned short* __restrict__ wq,  // limb layout (see convert_w)
    const float* __restrict__ bias,
    const float* __restrict__ pw,           // MODE 1
    unsigned int* __restrict__ opacked,     // MODE 0
    float* __restrict__ logdur)             // MODE 1
{
    __shared__ __align__(16) char lds[74048];
    char* XsH = lds;                  // 130 rows * 80B = 10400
    char* XsL = lds + 10400;
    char* WsH = lds + 20800;          // 128 rows * 208B = 26624
    char* WsL = lds + 47424;

    const int tid  = threadIdx.x;
    const int t0   = blockIdx.x * 128;
    const int o0   = blockIdx.y * 128;
    const int b    = blockIdx.z;
    const int lane = tid & 63;
    const int wave = tid >> 6;
    const int r    = lane & 15;       // frag row (A: time) / col (B: oc)
    const int g    = lane >> 4;       // k-group (8 bf16)
    const int wm   = wave >> 1;       // wave row (time)
    const int wn   = wave & 1;        // wave col (oc)

    const size_t abase = (size_t)b * T_ * H_;

    floatx4 acc[4][4];
    #pragma unroll
    for (int fn = 0; fn < 4; ++fn) {
        float bv = bias[o0 + wn * 64 + fn * 16 + r];
        #pragma unroll
        for (int fm = 0; fm < 4; ++fm)
            acc[fm][fn] = (floatx4){bv, bv, bv, bv};
    }

    for (int ic0 = 0; ic0 < H_; ic0 += 32) {
        __syncthreads();
        // ---- stage X halo chunk: rows 0..129 <-> global t0-1+row, 32 ic ----
        for (int p = tid; p < 520; p += 256) {
            int row = p >> 2, grp = p & 3;
            int gt = t0 - 1 + row;
            short8v hv = {0, 0, 0, 0, 0, 0, 0, 0};
            short8v lv = {0, 0, 0, 0, 0, 0, 0, 0};
            if (gt >= 0 && gt < T_) {
                if constexpr (MODE == 0) {
                    const float4* s =
                        (const float4*)(xin + abase + (size_t)gt * H_ + ic0 + grp * 8);
                    float4 a = s[0], c = s[1];
                    float vv[8] = {a.x, a.y, a.z, a.w, c.x, c.y, c.z, c.w};
                    #pragma unroll
                    for (int j = 0; j < 8; ++j) {
                        unsigned short h = f2bf_rne(vv[j]);
                        hv[j] = (short)h;
                        lv[j] = (short)f2bf_rne(vv[j] - bf2f(h));
                    }
                } else {
                    const uint4* s =
                        (const uint4*)(pin + abase + (size_t)gt * H_ + ic0 + grp * 8);
                    uint4 a = s[0], c = s[1];
                    unsigned int uu[8] = {a.x, a.y, a.z, a.w, c.x, c.y, c.z, c.w};
                    #pragma unroll
                    for (int j = 0; j < 8; ++j) {
                        hv[j] = (short)(uu[j] & 0xffffu);
                        lv[j] = (short)(uu[j] >> 16);
                    }
                }
            }
            int off = row * 80 + grp * 16;
            *(short8v*)(XsH + off) = hv;
            *(short8v*)(XsL + off) = lv;
        }
        // ---- stage W chunk: coalesced 16B reads from limb layout ----
        {
            const unsigned short* wqc = wq + (size_t)(ic0 >> 5) * 49152;
            #pragma unroll
            for (int it = 0; it < 12; ++it) {
                int p = tid + it * 256;
                int oc = p & 127;
                int j = p >> 7;                 // 0..23
                int arr = (j >= 12);
                int jj = j - arr * 12;
                int tap = jj >> 2, grp = jj & 3;
                const unsigned short* src =
                    wqc + ((((size_t)arr * 3 + tap) * 4 + grp) * 256 + o0 + oc) * 8;
                uint4 val = *(const uint4*)src;
                char* dst = (arr ? WsL : WsH) + oc * 208 + tap * 64 + grp * 16;
                *(uint4*)dst = val;
            }
        }
        __syncthreads();

        // ---- MFMA phase: 3 taps x 16 frag-pairs x 3 split terms ----
        #pragma unroll
        for (int tap = 0; tap < 3; ++tap) {
            short8v aH[4], aL[4], bH[4], bL[4];
            #pragma unroll
            for (int fm = 0; fm < 4; ++fm) {
                int off = (wm * 64 + fm * 16 + r + tap) * 80 + g * 16;
                aH[fm] = *(const short8v*)(XsH + off);
                aL[fm] = *(const short8v*)(XsL + off);
            }
            #pragma unroll
            for (int fn = 0; fn < 4; ++fn) {
                int off = (wn * 64 + fn * 16 + r) * 208 + tap * 64 + g * 16;
                bH[fn] = *(const short8v*)(WsH + off);
                bL[fn] = *(const short8v*)(WsL + off);
            }
            #pragma unroll
            for (int fm = 0; fm < 4; ++fm)
                #pragma unroll
                for (int fn = 0; fn < 4; ++fn) {
                    acc[fm][fn] = __builtin_amdgcn_mfma_f32_16x16x32_bf16(
                        aH[fm], bH[fn], acc[fm][fn], 0, 0, 0);
                    acc[fm][fn] = __builtin_amdgcn_mfma_f32_16x16x32_bf16(
                        aH[fm], bL[fn], acc[fm][fn], 0, 0, 0);
                    acc[fm][fn] = __builtin_amdgcn_mfma_f32_16x16x32_bf16(
                        aL[fm], bH[fn], acc[fm][fn], 0, 0, 0);
                }
        }
    }

    // ---- epilogue (C/D: col=lane&15 -> oc, row=(lane>>4)*4+reg -> t) ----
    if constexpr (MODE == 0) {
        unsigned int* ob = opacked + abase;
        #pragma unroll
        for (int fm = 0; fm < 4; ++fm) {
            int trow = t0 + wm * 64 + fm * 16 + g * 4;
            #pragma unroll
            for (int fn = 0; fn < 4; ++fn) {
                int o = o0 + wn * 64 + fn * 16 + r;
                #pragma unroll
                for (int reg = 0; reg < 4; ++reg) {
                    float v = fmaxf(acc[fm][fn][reg], 0.f);
                    unsigned short h = f2bf_rne(v);
                    unsigned short l = f2bf_rne(v - bf2f(h));
                    ob[(size_t)(trow + reg) * H_ + o] =
                        (unsigned int)h | ((unsigned int)l << 16);
                }
            }
        }
    } else {
        float pwv[4];
        #pragma unroll
        for (int fn = 0; fn < 4; ++fn) pwv[fn] = pw[o0 + wn * 64 + fn * 16 + r];
        #pragma unroll
        for (int fm = 0; fm < 4; ++fm) {
            #pragma unroll
            for (int reg = 0; reg < 4; ++reg) {
                float s = 0.f;
                #pragma unroll
                for (int fn = 0; fn < 4; ++fn)
                    s += fmaxf(acc[fm][fn][reg], 0.f) * pwv[fn];
                s += __shfl_xor(s, 1, 64);
                s += __shfl_xor(s, 2, 64);
                s += __shfl_xor(s, 4, 64);
                s += __shfl_xor(s, 8, 64);
                if (r == 0)
                    atomicAdd(&logdur[(size_t)b * T_ + t0 + wm * 64 + fm * 16 + g * 4 + reg], s);
            }
        }
    }
}

// ---------------------------------------------------------------------------
// Length regulator (verified in R1/R2).
// ---------------------------------------------------------------------------
__global__ __launch_bounds__(256) void regulator_kernel(
    const float* __restrict__ x, const int* __restrict__ dur,
    float* __restrict__ out)
{
    const int b  = blockIdx.y;
    const int r0 = blockIdx.x * 128;
    const int tid = threadIdx.x;
    const int lane = tid & 63;
    const int wv = tid >> 6;

    __shared__ int cum[T_];
    __shared__ int wtot[4];
    __shared__ int sidx[128];

    const int* drow = dur + (size_t)b * T_;
    int base = tid * 4;
    int d0 = drow[base + 0], d1 = drow[base + 1], d2 = drow[base + 2], d3 = drow[base + 3];
    int i0 = d0, i1 = i0 + d1, i2 = i1 + d2, i3 = i2 + d3;
    int lt = i3;
    int v = lt;
    #pragma unroll
    for (int delta = 1; delta < 64; delta <<= 1) {
        int u = __shfl_up(v, delta, 64);
        if (lane >= delta) v += u;
    }
    if (lane == 63) wtot[wv] = v;
    __syncthreads();
    int woff = 0;
    #pragma unroll
    for (int i = 0; i < 4; ++i)
        if (i < wv) woff += wtot[i];
    int excl = woff + v - lt;
    cum[base + 0] = excl + i0;
    cum[base + 1] = excl + i1;
    cum[base + 2] = excl + i2;
    cum[base + 3] = excl + i3;
    __syncthreads();

    int tot = cum[T_ - 1];
    if (tid < 128) {
        int p = r0 + tid;
        int lo = 0, hi = T_;
        while (lo < hi) {
            int mid = (lo + hi) >> 1;
            if (cum[mid] <= p) lo = mid + 1; else hi = mid;
        }
        int idx = lo > (T_ - 1) ? (T_ - 1) : lo;
        sidx[tid] = (p < tot) ? idx : -1;
    }
    __syncthreads();

    const float4* x4 = (const float4*)(x + (size_t)b * T_ * H_);
    float4* o4 = (float4*)(out + ((size_t)b * OUT_LEN_ + r0) * H_);
    for (int rr = 0; rr < 128; rr += 4) {
        int rw = rr + wv;
        int idx = sidx[rw];
        float4 val;
        if (idx >= 0) val = x4[(size_t)idx * (H_ / 4) + lane];
        else          val = make_float4(0.f, 0.f, 0.f, 0.f);
        o4[(size_t)rw * (H_ / 4) + lane] = val;
    }
}

// ---------------------------------------------------------------------------
extern "C" void kernel_launch(void* const* d_in, const int* in_sizes, int n_in,
                              void* d_out, int out_size, void* d_ws, size_t ws_size,
                              hipStream_t stream) {
    const float* x   = (const float*)d_in[0];
    const int*   dur = (const int*)d_in[1];
    const float* w1  = (const float*)d_in[2];
    const float* b1  = (const float*)d_in[3];
    const float* w2  = (const float*)d_in[4];
    const float* b2  = (const float*)d_in[5];
    const float* pw  = (const float*)d_in[6];
    const float* pb  = (const float*)d_in[7];

    float* out = (float*)d_out;                       // [B][OUT_LEN][H] + [B][T]
    char*  p   = (char*)d_out;

    // Scratch inside d_out (201.6 MB). h1p dead once conv2 finishes;
    // regulator overwrites [0, 201.3MB) last.
    unsigned int*   h1p = (unsigned int*)(p);                   // 67.1 MB packed bf16 hi|lo
    unsigned short* wq1 = (unsigned short*)(p + 134217728u);    // 786 KB limb layout
    unsigned short* wq2 = (unsigned short*)(p + 135004160u);    // 786 KB
    float* logdur = out + (size_t)B_ * OUT_LEN_ * H_;           // real output tail

    convert_w_kernel<<<768, 256, 0, stream>>>(w1, wq1);
    convert_w_kernel<<<768, 256, 0, stream>>>(w2, wq2);
    init_ld_kernel<<<(B_ * T_) / 256, 256, 0, stream>>>(logdur, pb);

    dim3 cgrid(T_ / 128, H_ / 128, B_);
    conv_mfma_kernel<0><<<cgrid, 256, 0, stream>>>(
        x, nullptr, wq1, b1, nullptr, h1p, nullptr);
    conv_mfma_kernel<1><<<cgrid, 256, 0, stream>>>(
        nullptr, h1p, wq2, b2, pw, nullptr, logdur);

    regulator_kernel<<<dim3(OUT_LEN_ / 128, B_), 256, 0, stream>>>(x, dur, out);
}

// Round 4
// 397.372 us; speedup vs baseline: 2.3566x; 1.0190x over previous
//
#include <hip/hip_runtime.h>
#include <hip/hip_bf16.h>

#define B_  64
#define T_  1024
#define H_  256
#define OUT_LEN_ 3072

typedef __attribute__((ext_vector_type(8))) short short8v;
typedef __attribute__((ext_vector_type(4))) float floatx4;

__device__ __forceinline__ unsigned short f2bf_rne(float f) {
    unsigned int u = __float_as_uint(f);
    u += 0x7FFFu + ((u >> 16) & 1u);
    return (unsigned short)(u >> 16);
}
__device__ __forceinline__ float bf2f(unsigned short h) {
    return __uint_as_float(((unsigned int)h) << 16);
}

// global -> LDS direct copy, 16B per lane. LDS dest must be wave-uniform
// base (+ lane*16 implicit); global src is per-lane.
__device__ __forceinline__ void gload_lds16(const void* g, void* l) {
    __builtin_amdgcn_global_load_lds(
        (const __attribute__((address_space(1))) unsigned int*)g,
        (__attribute__((address_space(3))) unsigned int*)l, 16, 0, 0);
}

// ---------------------------------------------------------------------------
// w[O][I][3] fp32 -> wq bf16 hi/lo limbs:
// idx(c,arr,tap,grp,o,el) = ((((c*2+arr)*3+tap)*4+grp)*256 + o)*8 + el
// (ic = c*32 + grp*8 + el). 16B chunks are contiguous across o -> the conv
// W-stage is a pure lane-linear global_load_lds.
// ---------------------------------------------------------------------------
__global__ __launch_bounds__(256) void convert_w_kernel(
    const float* __restrict__ w, unsigned short* __restrict__ wq)
{
    int e = blockIdx.x * 256 + threadIdx.x;
    if (e >= H_ * H_ * 3) return;
    int o = e / (H_ * 3);
    int rem = e - o * (H_ * 3);
    int ic = rem / 3;
    int tap = rem - ic * 3;
    float v = w[e];
    unsigned short h = f2bf_rne(v);
    unsigned short l = f2bf_rne(v - bf2f(h));
    int c = ic >> 5, grp = (ic >> 3) & 3, el = ic & 7;
    size_t hi_idx = ((((size_t)(c * 2 + 0) * 3 + tap) * 4 + grp) * 256 + o) * 8 + el;
    size_t lo_idx = ((((size_t)(c * 2 + 1) * 3 + tap) * 4 + grp) * 256 + o) * 8 + el;
    wq[hi_idx] = h;
    wq[lo_idx] = l;
}

// ---------------------------------------------------------------------------
__global__ __launch_bounds__(256) void init_ld_kernel(float* __restrict__ ld,
                                                      const float* __restrict__ pb) {
    int i = blockIdx.x * 256 + threadIdx.x;
    if (i < B_ * T_) ld[i] = pb[0];
}

// ---------------------------------------------------------------------------
// Conv1d(K=3, SAME) + bias + ReLU, split-precision bf16 MFMA (hh+hl+lh).
// Block 128t x 128oc, 4 waves (2x2), wave tile 64x64 (4x4 frags 16x16x32),
// ic chunks of 32.
// X: reg-staged (inline fp32->bf16 split / u32 unpack), rows 80B padded
//    (20 dw ≡ 20 mod 32 -> bank period 8, b128 reads 2-way = free).
// W: global_load_lds direct, LDS [limb][tap][grp][oc][16B] linear;
//    B-frag reads are consecutive-16B across lanes (2-way = free).
// MODE 0: in fp32 x, out packed u32 (bf16 hi | lo<<16).
// MODE 1: in packed u32, epilogue fuses projection (logdur += relu(v)*pw).
// ---------------------------------------------------------------------------
template <int MODE>
__global__ __launch_bounds__(256, 2) void conv_mfma_kernel(
    const float* __restrict__ xin,          // MODE 0
    const unsigned int* __restrict__ pin,   // MODE 1
    const unsigned short* __restrict__ wq,  // limb layout (see convert_w)
    const float* __restrict__ bias,
    const float* __restrict__ pw,           // MODE 1
    unsigned int* __restrict__ opacked,     // MODE 0
    float* __restrict__ logdur)             // MODE 1
{
    __shared__ __align__(16) char lds[69952];
    char* XsH = lds;                  // 130 rows * 80B = 10400
    char* XsL = lds + 10400;          // 10400
    char* Ws  = lds + 20800;          // 2*3*4*128 chunks * 16B = 49152

    const int tid  = threadIdx.x;
    const int t0   = blockIdx.x * 128;
    const int o0   = blockIdx.y * 128;
    const int b    = blockIdx.z;
    const int lane = tid & 63;
    const int wave = tid >> 6;
    const int r    = lane & 15;       // frag row (A: time) / col (B: oc)
    const int g    = lane >> 4;       // k-group (8 bf16)
    const int wm   = wave >> 1;       // wave row (time)
    const int wn   = wave & 1;        // wave col (oc)

    const size_t abase = (size_t)b * T_ * H_;

    floatx4 acc[4][4];
    #pragma unroll
    for (int fn = 0; fn < 4; ++fn) {
        float bv = bias[o0 + wn * 64 + fn * 16 + r];
        #pragma unroll
        for (int fm = 0; fm < 4; ++fm)
            acc[fm][fn] = (floatx4){bv, bv, bv, bv};
    }

    for (int ic0 = 0; ic0 < H_; ic0 += 32) {
        __syncthreads();
        // ---- stage W chunk: 48 wave-level global_load_lds (12 per wave) ----
        {
            const unsigned short* wqc = wq + (size_t)(ic0 >> 5) * 49152;
            #pragma unroll
            for (int it = 0; it < 12; ++it) {
                int wl = wave * 12 + it;       // 0..47
                int half = wl & 1;             // which 64-oc half
                int atg = wl >> 1;             // (arr*3+tap)*4+grp, 0..23
                const unsigned short* src =
                    wqc + ((size_t)atg * 256 + o0 + half * 64 + lane) * 8;
                char* dst = Ws + (size_t)(atg * 128 + half * 64) * 16;
                gload_lds16(src, dst);
            }
        }
        // ---- stage X halo chunk: rows 0..129 <-> global t0-1+row, 32 ic ----
        for (int p = tid; p < 520; p += 256) {
            int row = p >> 2, grp = p & 3;
            int gt = t0 - 1 + row;
            short8v hv = {0, 0, 0, 0, 0, 0, 0, 0};
            short8v lv = {0, 0, 0, 0, 0, 0, 0, 0};
            if (gt >= 0 && gt < T_) {
                if constexpr (MODE == 0) {
                    const float4* s =
                        (const float4*)(xin + abase + (size_t)gt * H_ + ic0 + grp * 8);
                    float4 a = s[0], c = s[1];
                    float vv[8] = {a.x, a.y, a.z, a.w, c.x, c.y, c.z, c.w};
                    #pragma unroll
                    for (int j = 0; j < 8; ++j) {
                        unsigned short h = f2bf_rne(vv[j]);
                        hv[j] = (short)h;
                        lv[j] = (short)f2bf_rne(vv[j] - bf2f(h));
                    }
                } else {
                    const uint4* s =
                        (const uint4*)(pin + abase + (size_t)gt * H_ + ic0 + grp * 8);
                    uint4 a = s[0], c = s[1];
                    unsigned int uu[8] = {a.x, a.y, a.z, a.w, c.x, c.y, c.z, c.w};
                    #pragma unroll
                    for (int j = 0; j < 8; ++j) {
                        hv[j] = (short)(uu[j] & 0xffffu);
                        lv[j] = (short)(uu[j] >> 16);
                    }
                }
            }
            int off = row * 80 + grp * 16;
            *(short8v*)(XsH + off) = hv;
            *(short8v*)(XsL + off) = lv;
        }
        __syncthreads();

        // ---- MFMA phase: 3 taps x 16 frag-pairs x 3 limb terms ----
        #pragma unroll
        for (int tap = 0; tap < 3; ++tap) {
            short8v aH[4], aL[4], bH[4], bL[4];
            #pragma unroll
            for (int fm = 0; fm < 4; ++fm) {
                int off = (wm * 64 + fm * 16 + r + tap) * 80 + g * 16;
                aH[fm] = *(const short8v*)(XsH + off);
                aL[fm] = *(const short8v*)(XsL + off);
            }
            #pragma unroll
            for (int fn = 0; fn < 4; ++fn) {
                int ocl = wn * 64 + fn * 16 + r;
                bH[fn] = *(const short8v*)(Ws + (size_t)(((0 * 3 + tap) * 4 + g) * 128 + ocl) * 16);
                bL[fn] = *(const short8v*)(Ws + (size_t)(((1 * 3 + tap) * 4 + g) * 128 + ocl) * 16);
            }
            #pragma unroll
            for (int fm = 0; fm < 4; ++fm)
                #pragma unroll
                for (int fn = 0; fn < 4; ++fn) {
                    acc[fm][fn] = __builtin_amdgcn_mfma_f32_16x16x32_bf16(
                        aH[fm], bH[fn], acc[fm][fn], 0, 0, 0);
                    acc[fm][fn] = __builtin_amdgcn_mfma_f32_16x16x32_bf16(
                        aH[fm], bL[fn], acc[fm][fn], 0, 0, 0);
                    acc[fm][fn] = __builtin_amdgcn_mfma_f32_16x16x32_bf16(
                        aL[fm], bH[fn], acc[fm][fn], 0, 0, 0);
                }
        }
    }

    // ---- epilogue (C/D: col=lane&15 -> oc, row=(lane>>4)*4+reg -> t) ----
    if constexpr (MODE == 0) {
        unsigned int* ob = opacked + abase;
        #pragma unroll
        for (int fm = 0; fm < 4; ++fm) {
            int trow = t0 + wm * 64 + fm * 16 + g * 4;
            #pragma unroll
            for (int fn = 0; fn < 4; ++fn) {
                int o = o0 + wn * 64 + fn * 16 + r;
                #pragma unroll
                for (int reg = 0; reg < 4; ++reg) {
                    float v = fmaxf(acc[fm][fn][reg], 0.f);
                    unsigned short h = f2bf_rne(v);
                    unsigned short l = f2bf_rne(v - bf2f(h));
                    ob[(size_t)(trow + reg) * H_ + o] =
                        (unsigned int)h | ((unsigned int)l << 16);
                }
            }
        }
    } else {
        float pwv[4];
        #pragma unroll
        for (int fn = 0; fn < 4; ++fn) pwv[fn] = pw[o0 + wn * 64 + fn * 16 + r];
        #pragma unroll
        for (int fm = 0; fm < 4; ++fm) {
            #pragma unroll
            for (int reg = 0; reg < 4; ++reg) {
                float s = 0.f;
                #pragma unroll
                for (int fn = 0; fn < 4; ++fn)
                    s += fmaxf(acc[fm][fn][reg], 0.f) * pwv[fn];
                s += __shfl_xor(s, 1, 64);
                s += __shfl_xor(s, 2, 64);
                s += __shfl_xor(s, 4, 64);
                s += __shfl_xor(s, 8, 64);
                if (r == 0)
                    atomicAdd(&logdur[(size_t)b * T_ + t0 + wm * 64 + fm * 16 + g * 4 + reg], s);
            }
        }
    }
}

// ---------------------------------------------------------------------------
// Length regulator (verified in R1-R3).
// ---------------------------------------------------------------------------
__global__ __launch_bounds__(256) void regulator_kernel(
    const float* __restrict__ x, const int* __restrict__ dur,
    float* __restrict__ out)
{
    const int b  = blockIdx.y;
    const int r0 = blockIdx.x * 128;
    const int tid = threadIdx.x;
    const int lane = tid & 63;
    const int wv = tid >> 6;

    __shared__ int cum[T_];
    __shared__ int wtot[4];
    __shared__ int sidx[128];

    const int* drow = dur + (size_t)b * T_;
    int base = tid * 4;
    int d0 = drow[base + 0], d1 = drow[base + 1], d2 = drow[base + 2], d3 = drow[base + 3];
    int i0 = d0, i1 = i0 + d1, i2 = i1 + d2, i3 = i2 + d3;
    int lt = i3;
    int v = lt;
    #pragma unroll
    for (int delta = 1; delta < 64; delta <<= 1) {
        int u = __shfl_up(v, delta, 64);
        if (lane >= delta) v += u;
    }
    if (lane == 63) wtot[wv] = v;
    __syncthreads();
    int woff = 0;
    #pragma unroll
    for (int i = 0; i < 4; ++i)
        if (i < wv) woff += wtot[i];
    int excl = woff + v - lt;
    cum[base + 0] = excl + i0;
    cum[base + 1] = excl + i1;
    cum[base + 2] = excl + i2;
    cum[base + 3] = excl + i3;
    __syncthreads();

    int tot = cum[T_ - 1];
    if (tid < 128) {
        int p = r0 + tid;
        int lo = 0, hi = T_;
        while (lo < hi) {
            int mid = (lo + hi) >> 1;
            if (cum[mid] <= p) lo = mid + 1; else hi = mid;
        }
        int idx = lo > (T_ - 1) ? (T_ - 1) : lo;
        sidx[tid] = (p < tot) ? idx : -1;
    }
    __syncthreads();

    const float4* x4 = (const float4*)(x + (size_t)b * T_ * H_);
    float4* o4 = (float4*)(out + ((size_t)b * OUT_LEN_ + r0) * H_);
    for (int rr = 0; rr < 128; rr += 4) {
        int rw = rr + wv;
        int idx = sidx[rw];
        float4 val;
        if (idx >= 0) val = x4[(size_t)idx * (H_ / 4) + lane];
        else          val = make_float4(0.f, 0.f, 0.f, 0.f);
        o4[(size_t)rw * (H_ / 4) + lane] = val;
    }
}

// ---------------------------------------------------------------------------
extern "C" void kernel_launch(void* const* d_in, const int* in_sizes, int n_in,
                              void* d_out, int out_size, void* d_ws, size_t ws_size,
                              hipStream_t stream) {
    const float* x   = (const float*)d_in[0];
    const int*   dur = (const int*)d_in[1];
    const float* w1  = (const float*)d_in[2];
    const float* b1  = (const float*)d_in[3];
    const float* w2  = (const float*)d_in[4];
    const float* b2  = (const float*)d_in[5];
    const float* pw  = (const float*)d_in[6];
    const float* pb  = (const float*)d_in[7];

    float* out = (float*)d_out;                       // [B][OUT_LEN][H] + [B][T]
    char*  p   = (char*)d_out;

    // Scratch inside d_out (201.6 MB). h1p dead once conv2 finishes;
    // regulator overwrites [0, 201.3MB) last.
    unsigned int*   h1p = (unsigned int*)(p);                   // 67.1 MB packed bf16 hi|lo
    unsigned short* wq1 = (unsigned short*)(p + 134217728u);    // 786 KB limb layout
    unsigned short* wq2 = (unsigned short*)(p + 135004160u);    // 786 KB
    float* logdur = out + (size_t)B_ * OUT_LEN_ * H_;           // real output tail

    convert_w_kernel<<<768, 256, 0, stream>>>(w1, wq1);
    convert_w_kernel<<<768, 256, 0, stream>>>(w2, wq2);
    init_ld_kernel<<<(B_ * T_) / 256, 256, 0, stream>>>(logdur, pb);

    dim3 cgrid(T_ / 128, H_ / 128, B_);
    conv_mfma_kernel<0><<<cgrid, 256, 0, stream>>>(
        x, nullptr, wq1, b1, nullptr, h1p, nullptr);
    conv_mfma_kernel<1><<<cgrid, 256, 0, stream>>>(
        nullptr, h1p, wq2, b2, pw, nullptr, logdur);

    regulator_kernel<<<dim3(OUT_LEN_ / 128, B_), 256, 0, stream>>>(x, dur, out);
}

// Round 5
// 397.233 us; speedup vs baseline: 2.3575x; 1.0004x over previous
//
#include <hip/hip_runtime.h>
#include <hip/hip_bf16.h>

#define B_  64
#define T_  1024
#define H_  256
#define OUT_LEN_ 3072

typedef __attribute__((ext_vector_type(8))) short short8v;
typedef __attribute__((ext_vector_type(4))) float floatx4;

__device__ __forceinline__ unsigned short f2bf_rne(float f) {
    unsigned int u = __float_as_uint(f);
    u += 0x7FFFu + ((u >> 16) & 1u);
    return (unsigned short)(u >> 16);
}
__device__ __forceinline__ float bf2f(unsigned short h) {
    return __uint_as_float(((unsigned int)h) << 16);
}

// ---------------------------------------------------------------------------
// w[O][I][3] fp32 -> wq bf16 hi/lo limbs:
// idx(c,arr,tap,grp,o,el) = ((((c*2+arr)*3+tap)*4+grp)*256 + o)*8 + el
// (ic = c*32 + grp*8 + el). Each 16B chunk at fixed (c,arr,tap,grp) is
// contiguous across o -> B-fragments load straight from global, coalesced.
// ---------------------------------------------------------------------------
__global__ __launch_bounds__(256) void convert_w_kernel(
    const float* __restrict__ w, unsigned short* __restrict__ wq)
{
    int e = blockIdx.x * 256 + threadIdx.x;
    if (e >= H_ * H_ * 3) return;
    int o = e / (H_ * 3);
    int rem = e - o * (H_ * 3);
    int ic = rem / 3;
    int tap = rem - ic * 3;
    float v = w[e];
    unsigned short h = f2bf_rne(v);
    unsigned short l = f2bf_rne(v - bf2f(h));
    int c = ic >> 5, grp = (ic >> 3) & 3, el = ic & 7;
    size_t hi_idx = ((((size_t)(c * 2 + 0) * 3 + tap) * 4 + grp) * 256 + o) * 8 + el;
    size_t lo_idx = ((((size_t)(c * 2 + 1) * 3 + tap) * 4 + grp) * 256 + o) * 8 + el;
    wq[hi_idx] = h;
    wq[lo_idx] = l;
}

// ---------------------------------------------------------------------------
__global__ __launch_bounds__(256) void init_ld_kernel(float* __restrict__ ld,
                                                      const float* __restrict__ pb) {
    int i = blockIdx.x * 256 + threadIdx.x;
    if (i < B_ * T_) ld[i] = pb[0];
}

// ---------------------------------------------------------------------------
// Conv1d(K=3, SAME) + bias + ReLU, split-precision bf16 MFMA (hh+hl+lh).
// Block 128t x 128oc, 4 waves (2x2), wave tile 64x64 (4x4 frags 16x16x32),
// ic chunks of 32, software-pipelined:
//   per chunk c: issue X loads(c+1) -> regs | W global->reg loads (L2) +
//   ds_read A from Xs[c&1] + 144 MFMA | convert+ds_write Xs[(c+1)&1] |
//   ONE barrier.
// X LDS double-buffered, rows 80B padded (bank period 8 -> b128 reads free).
// W never touches LDS (limb layout = per-lane fragments, L2-resident).
// MODE 0: in fp32 x, out packed u32 (bf16 hi | lo<<16).
// MODE 1: in packed u32, epilogue fuses projection (logdur += relu(v)*pw).
// ---------------------------------------------------------------------------
template <int MODE>
__global__ __launch_bounds__(256, 2) void conv_mfma_kernel(
    const float* __restrict__ xin,          // MODE 0
    const unsigned int* __restrict__ pin,   // MODE 1
    const unsigned short* __restrict__ wq,  // limb layout (see convert_w)
    const float* __restrict__ bias,
    const float* __restrict__ pw,           // MODE 1
    unsigned int* __restrict__ opacked,     // MODE 0
    float* __restrict__ logdur)             // MODE 1
{
    __shared__ __align__(16) char lds[2][20800];   // per buf: XsH 10400 | XsL 10400

    const int tid  = threadIdx.x;
    const int t0   = blockIdx.x * 128;
    const int o0   = blockIdx.y * 128;
    const int b    = blockIdx.z;
    const int lane = tid & 63;
    const int wave = tid >> 6;
    const int r    = lane & 15;       // frag row (A: time) / col (B: oc)
    const int g    = lane >> 4;       // k-group (8 bf16)
    const int wm   = wave >> 1;       // wave row (time)
    const int wn   = wave & 1;        // wave col (oc)

    const size_t abase = (size_t)b * T_ * H_;

    // X staging item ownership: it0: (row=tid>>2, grp=tid&3); it1: row+64;
    // it2 (tid<8): rows 128..129.
    const int srow0 = tid >> 2, sgrp = tid & 3;
    const int gt0 = t0 - 1 + srow0;
    const int gt1 = gt0 + 64;
    const int gt2 = t0 - 1 + 128 + (tid >> 2);     // only tid<8
    const bool v0 = (gt0 >= 0) && (gt0 < T_);
    const bool v1 = (gt1 < T_);
    const bool v2 = (tid < 8) && (gt2 < T_);

    // W per-lane fragment base: frag(c2,arr,tap,fn) =
    //   wb + (c2*24 + arr*12 + tap*4)*2048 + fn*128   (ushort units: *1)
    const unsigned short* wb = wq + (size_t)g * 2048 + (size_t)(o0 + wn * 64 + r) * 8;

    floatx4 acc[4][4];
    #pragma unroll
    for (int fn = 0; fn < 4; ++fn) {
        float bv = bias[o0 + wn * 64 + fn * 16 + r];
        #pragma unroll
        for (int fm = 0; fm < 4; ++fm)
            acc[fm][fn] = (floatx4){bv, bv, bv, bv};
    }

    // ---- X stage helper (macro-ish lambdas, static control flow) ----
    auto stage_commit = [&](int buf, short8v h0, short8v l0, short8v h1,
                            short8v l1, short8v h2, short8v l2) {
        char* XsH = lds[buf];
        char* XsL = lds[buf] + 10400;
        int off0 = srow0 * 80 + sgrp * 16;
        *(short8v*)(XsH + off0) = h0;
        *(short8v*)(XsL + off0) = l0;
        int off1 = off0 + 64 * 80;
        *(short8v*)(XsH + off1) = h1;
        *(short8v*)(XsL + off1) = l1;
        if (tid < 8) {
            int off2 = (128 + (tid >> 2)) * 80 + sgrp * 16;
            *(short8v*)(XsH + off2) = h2;
            *(short8v*)(XsL + off2) = l2;
        }
    };

    #define LOAD_X_F32(gt, valid, ra, rb)                                        \
        if (valid) {                                                             \
            const float4* s = (const float4*)(xin + abase + (size_t)(gt) * H_ +  \
                                              ic_n + sgrp * 8);                  \
            ra = s[0]; rb = s[1];                                                \
        }
    #define LOAD_X_U32(gt, valid, ra, rb)                                        \
        if (valid) {                                                             \
            const uint4* s = (const uint4*)(pin + abase + (size_t)(gt) * H_ +    \
                                            ic_n + sgrp * 8);                    \
            ra = s[0]; rb = s[1];                                                \
        }
    #define CVT_F32(ra, rb, hv, lv)                                              \
        {                                                                        \
            float vv[8] = {ra.x, ra.y, ra.z, ra.w, rb.x, rb.y, rb.z, rb.w};      \
            _Pragma("unroll")                                                    \
            for (int j = 0; j < 8; ++j) {                                        \
                unsigned short h = f2bf_rne(vv[j]);                              \
                hv[j] = (short)h;                                                \
                lv[j] = (short)f2bf_rne(vv[j] - bf2f(h));                        \
            }                                                                    \
        }
    #define CVT_U32(ra, rb, hv, lv)                                              \
        {                                                                        \
            unsigned int uu[8] = {ra.x, ra.y, ra.z, ra.w, rb.x, rb.y, rb.z, rb.w};\
            _Pragma("unroll")                                                    \
            for (int j = 0; j < 8; ++j) {                                        \
                hv[j] = (short)(uu[j] & 0xffffu);                                \
                lv[j] = (short)(uu[j] >> 16);                                    \
            }                                                                    \
        }

    // ---- prologue: stage chunk 0 into buf 0 ----
    {
        const int ic_n = 0;
        float4 fa0{}, fb0{}, fa1{}, fb1{}, fa2{}, fb2{};
        uint4  ua0{}, ub0{}, ua1{}, ub1{}, ua2{}, ub2{};
        if constexpr (MODE == 0) {
            LOAD_X_F32(gt0, v0, fa0, fb0);
            LOAD_X_F32(gt1, v1, fa1, fb1);
            LOAD_X_F32(gt2, v2, fa2, fb2);
        } else {
            LOAD_X_U32(gt0, v0, ua0, ub0);
            LOAD_X_U32(gt1, v1, ua1, ub1);
            LOAD_X_U32(gt2, v2, ua2, ub2);
        }
        short8v h0{}, l0{}, h1{}, l1{}, h2{}, l2{};
        if constexpr (MODE == 0) {
            CVT_F32(fa0, fb0, h0, l0);
            CVT_F32(fa1, fb1, h1, l1);
            CVT_F32(fa2, fb2, h2, l2);
        } else {
            CVT_U32(ua0, ub0, h0, l0);
            CVT_U32(ua1, ub1, h1, l1);
            CVT_U32(ua2, ub2, h2, l2);
        }
        stage_commit(0, h0, l0, h1, l1, h2, l2);
    }
    __syncthreads();

    // ---- main pipeline over 8 ic-chunks ----
    #pragma unroll 2
    for (int c = 0; c < 8; ++c) {
        const int cur = c & 1;
        const bool pf = (c < 7);
        const int ic_n = (c + 1) * 32;

        // issue next-chunk X loads (latency hides under this chunk's MFMAs)
        float4 fa0{}, fb0{}, fa1{}, fb1{}, fa2{}, fb2{};
        uint4  ua0{}, ub0{}, ua1{}, ub1{}, ua2{}, ub2{};
        if (pf) {
            if constexpr (MODE == 0) {
                LOAD_X_F32(gt0, v0, fa0, fb0);
                LOAD_X_F32(gt1, v1, fa1, fb1);
                LOAD_X_F32(gt2, v2, fa2, fb2);
            } else {
                LOAD_X_U32(gt0, v0, ua0, ub0);
                LOAD_X_U32(gt1, v1, ua1, ub1);
                LOAD_X_U32(gt2, v2, ua2, ub2);
            }
        }

        // compute phase: per tap, 8 W global loads (L2) + 8 A ds_reads + 48 MFMA
        const char* XsH = lds[cur];
        const char* XsL = lds[cur] + 10400;
        const unsigned short* wc = wb + (size_t)c * 24 * 2048;
        const int arow = (wm * 64 + r) * 80 + g * 16;
        #pragma unroll
        for (int tap = 0; tap < 3; ++tap) {
            short8v aH[4], aL[4], bH[4], bL[4];
            #pragma unroll
            for (int fn = 0; fn < 4; ++fn) {
                bH[fn] = *(const short8v*)(wc + (size_t)tap * 4 * 2048 + fn * 128);
                bL[fn] = *(const short8v*)(wc + (size_t)(12 + tap * 4) * 2048 + fn * 128);
            }
            #pragma unroll
            for (int fm = 0; fm < 4; ++fm) {
                int off = arow + (fm * 16 + tap) * 80;
                aH[fm] = *(const short8v*)(XsH + off);
                aL[fm] = *(const short8v*)(XsL + off);
            }
            #pragma unroll
            for (int fm = 0; fm < 4; ++fm)
                #pragma unroll
                for (int fn = 0; fn < 4; ++fn) {
                    acc[fm][fn] = __builtin_amdgcn_mfma_f32_16x16x32_bf16(
                        aH[fm], bH[fn], acc[fm][fn], 0, 0, 0);
                    acc[fm][fn] = __builtin_amdgcn_mfma_f32_16x16x32_bf16(
                        aH[fm], bL[fn], acc[fm][fn], 0, 0, 0);
                    acc[fm][fn] = __builtin_amdgcn_mfma_f32_16x16x32_bf16(
                        aL[fm], bH[fn], acc[fm][fn], 0, 0, 0);
                }
        }

        // commit next-chunk X into the other buffer
        if (pf) {
            short8v h0{}, l0{}, h1{}, l1{}, h2{}, l2{};
            if constexpr (MODE == 0) {
                CVT_F32(fa0, fb0, h0, l0);
                CVT_F32(fa1, fb1, h1, l1);
                CVT_F32(fa2, fb2, h2, l2);
            } else {
                CVT_U32(ua0, ub0, h0, l0);
                CVT_U32(ua1, ub1, h1, l1);
                CVT_U32(ua2, ub2, h2, l2);
            }
            stage_commit(cur ^ 1, h0, l0, h1, l1, h2, l2);
        }
        __syncthreads();
    }

    // ---- epilogue (C/D: col=lane&15 -> oc, row=(lane>>4)*4+reg -> t) ----
    if constexpr (MODE == 0) {
        unsigned int* ob = opacked + abase;
        #pragma unroll
        for (int fm = 0; fm < 4; ++fm) {
            int trow = t0 + wm * 64 + fm * 16 + g * 4;
            #pragma unroll
            for (int fn = 0; fn < 4; ++fn) {
                int o = o0 + wn * 64 + fn * 16 + r;
                #pragma unroll
                for (int reg = 0; reg < 4; ++reg) {
                    float v = fmaxf(acc[fm][fn][reg], 0.f);
                    unsigned short h = f2bf_rne(v);
                    unsigned short l = f2bf_rne(v - bf2f(h));
                    ob[(size_t)(trow + reg) * H_ + o] =
                        (unsigned int)h | ((unsigned int)l << 16);
                }
            }
        }
    } else {
        float pwv[4];
        #pragma unroll
        for (int fn = 0; fn < 4; ++fn) pwv[fn] = pw[o0 + wn * 64 + fn * 16 + r];
        #pragma unroll
        for (int fm = 0; fm < 4; ++fm) {
            #pragma unroll
            for (int reg = 0; reg < 4; ++reg) {
                float s = 0.f;
                #pragma unroll
                for (int fn = 0; fn < 4; ++fn)
                    s += fmaxf(acc[fm][fn][reg], 0.f) * pwv[fn];
                s += __shfl_xor(s, 1, 64);
                s += __shfl_xor(s, 2, 64);
                s += __shfl_xor(s, 4, 64);
                s += __shfl_xor(s, 8, 64);
                if (r == 0)
                    atomicAdd(&logdur[(size_t)b * T_ + t0 + wm * 64 + fm * 16 + g * 4 + reg], s);
            }
        }
    }
}

// ---------------------------------------------------------------------------
// Length regulator (verified in R1-R4).
// ---------------------------------------------------------------------------
__global__ __launch_bounds__(256) void regulator_kernel(
    const float* __restrict__ x, const int* __restrict__ dur,
    float* __restrict__ out)
{
    const int b  = blockIdx.y;
    const int r0 = blockIdx.x * 128;
    const int tid = threadIdx.x;
    const int lane = tid & 63;
    const int wv = tid >> 6;

    __shared__ int cum[T_];
    __shared__ int wtot[4];
    __shared__ int sidx[128];

    const int* drow = dur + (size_t)b * T_;
    int base = tid * 4;
    int d0 = drow[base + 0], d1 = drow[base + 1], d2 = drow[base + 2], d3 = drow[base + 3];
    int i0 = d0, i1 = i0 + d1, i2 = i1 + d2, i3 = i2 + d3;
    int lt = i3;
    int v = lt;
    #pragma unroll
    for (int delta = 1; delta < 64; delta <<= 1) {
        int u = __shfl_up(v, delta, 64);
        if (lane >= delta) v += u;
    }
    if (lane == 63) wtot[wv] = v;
    __syncthreads();
    int woff = 0;
    #pragma unroll
    for (int i = 0; i < 4; ++i)
        if (i < wv) woff += wtot[i];
    int excl = woff + v - lt;
    cum[base + 0] = excl + i0;
    cum[base + 1] = excl + i1;
    cum[base + 2] = excl + i2;
    cum[base + 3] = excl + i3;
    __syncthreads();

    int tot = cum[T_ - 1];
    if (tid < 128) {
        int p = r0 + tid;
        int lo = 0, hi = T_;
        while (lo < hi) {
            int mid = (lo + hi) >> 1;
            if (cum[mid] <= p) lo = mid + 1; else hi = mid;
        }
        int idx = lo > (T_ - 1) ? (T_ - 1) : lo;
        sidx[tid] = (p < tot) ? idx : -1;
    }
    __syncthreads();

    const float4* x4 = (const float4*)(x + (size_t)b * T_ * H_);
    float4* o4 = (float4*)(out + ((size_t)b * OUT_LEN_ + r0) * H_);
    for (int rr = 0; rr < 128; rr += 4) {
        int rw = rr + wv;
        int idx = sidx[rw];
        float4 val;
        if (idx >= 0) val = x4[(size_t)idx * (H_ / 4) + lane];
        else          val = make_float4(0.f, 0.f, 0.f, 0.f);
        o4[(size_t)rw * (H_ / 4) + lane] = val;
    }
}

// ---------------------------------------------------------------------------
extern "C" void kernel_launch(void* const* d_in, const int* in_sizes, int n_in,
                              void* d_out, int out_size, void* d_ws, size_t ws_size,
                              hipStream_t stream) {
    const float* x   = (const float*)d_in[0];
    const int*   dur = (const int*)d_in[1];
    const float* w1  = (const float*)d_in[2];
    const float* b1  = (const float*)d_in[3];
    const float* w2  = (const float*)d_in[4];
    const float* b2  = (const float*)d_in[5];
    const float* pw  = (const float*)d_in[6];
    const float* pb  = (const float*)d_in[7];

    float* out = (float*)d_out;                       // [B][OUT_LEN][H] + [B][T]
    char*  p   = (char*)d_out;

    // Scratch inside d_out (201.6 MB). h1p dead once conv2 finishes;
    // regulator overwrites [0, 201.3MB) last.
    unsigned int*   h1p = (unsigned int*)(p);                   // 67.1 MB packed bf16 hi|lo
    unsigned short* wq1 = (unsigned short*)(p + 134217728u);    // 786 KB limb layout
    unsigned short* wq2 = (unsigned short*)(p + 135004160u);    // 786 KB
    float* logdur = out + (size_t)B_ * OUT_LEN_ * H_;           // real output tail

    convert_w_kernel<<<768, 256, 0, stream>>>(w1, wq1);
    convert_w_kernel<<<768, 256, 0, stream>>>(w2, wq2);
    init_ld_kernel<<<(B_ * T_) / 256, 256, 0, stream>>>(logdur, pb);

    dim3 cgrid(T_ / 128, H_ / 128, B_);
    conv_mfma_kernel<0><<<cgrid, 256, 0, stream>>>(
        x, nullptr, wq1, b1, nullptr, h1p, nullptr);
    conv_mfma_kernel<1><<<cgrid, 256, 0, stream>>>(
        nullptr, h1p, wq2, b2, pw, nullptr, logdur);

    regulator_kernel<<<dim3(OUT_LEN_ / 128, B_), 256, 0, stream>>>(x, dur, out);
}